// Round 3
// baseline (450.672 us; speedup 1.0000x reference)
//
#include <hip/hip_runtime.h>

// Problem constants (reference: B=4, C=3, H=384, W=1248, FILTER_SIZE=3)
#define B_ 4
#define C_ 3
#define H_ 384
#define W_ 1248
#define F_ 3
#define KK_ 9               // F*F
#define W4_ (W_ / 4)        // 312

constexpr int N_FEAT = B_ * KK_ * C_ * H_ * W_;       // 51,757,056 per tensor
constexpr int NTOT4  = 2 * B_ * KK_ * C_ * H_ * W4_;  // 25,878,528 output float4s

// Native vector type (HIP float4 is a class type __builtin_nontemporal_store rejects).
typedef float vf4 __attribute__((ext_vector_type(4)));

// v4: LINEAR OUTPUT MAPPING. One thread per output float4; thread id == flat
// float4 index of out[s][b][k][c][y][x]. Stores sweep the 414 MB output as one
// contiguous device-wide stream (the pattern the harness's own fill kernel
// sustains at 6.3 TB/s). Each thread does ONE dwordx4 load from the L3-resident
// input (4B-aligned "unaligned" shift for dx!=1) and ONE nt dwordx4 store.
// k/dy/dx branches are wave-uniform (k period = 359,424 threads); only the
// x-edge patch (2 of 312 lane positions per row) diverges.
__global__ __launch_bounds__(256) void unfold9_lin(
    const float* __restrict__ left,
    const float* __restrict__ right,
    float* __restrict__ out)
{
    int t = blockIdx.x * blockDim.x + threadIdx.x;
    if (t >= NTOT4) return;

    int x4 = t % W4_;
    int r  = t / W4_;
    int y  = r % H_;  r /= H_;
    int c  = r % C_;  r /= C_;
    int k  = r % KK_; r /= KK_;
    int b  = r % B_;
    int s  = r / B_;

    const int dy  = k / 3;
    const int dx  = k % 3;
    const int yin = y + dy - 1;

    vf4 v = (vf4){0.f, 0.f, 0.f, 0.f};
    if (yin >= 0 && yin < H_) {
        const float* rp = (s ? right : left)
                        + (size_t)((b * C_ + c) * H_ + yin) * W_;
        const int x0 = x4 * 4;
        if (dx == 1) {                       // aligned: src x = [x0 .. x0+3]
            v = *reinterpret_cast<const vf4*>(rp + x0);
        } else if (dx == 0) {                // src x = [x0-1 .. x0+2]
            if (x4 > 0) {
                v = *reinterpret_cast<const vf4*>(rp + x0 - 1);
            } else {
                vf4 a = *reinterpret_cast<const vf4*>(rp);
                v = (vf4){0.f, a.x, a.y, a.z};
            }
        } else {                             // dx==2: src x = [x0+1 .. x0+4]
            if (x4 < W4_ - 1) {
                v = *reinterpret_cast<const vf4*>(rp + x0 + 1);
            } else {
                vf4 a = *reinterpret_cast<const vf4*>(rp + x0);
                v = (vf4){a.y, a.z, a.w, 0.f};
            }
        }
    }
    __builtin_nontemporal_store(v, reinterpret_cast<vf4*>(out) + t);
}

// one_hot_filter = eye(9).reshape(9,1,1,3,3): flat[i] = (i % 10 == 0)
__global__ void onehot_kernel(float* __restrict__ out)
{
    int i = threadIdx.x;
    if (i < KK_ * KK_) out[i] = (i % 10 == 0) ? 1.0f : 0.0f;
}

extern "C" void kernel_launch(void* const* d_in, const int* in_sizes, int n_in,
                              void* d_out, int out_size, void* d_ws, size_t ws_size,
                              hipStream_t stream)
{
    const float* left  = (const float*)d_in[0];
    const float* right = (const float*)d_in[1];
    float* out = (float*)d_out;

    int blocks = (NTOT4 + 255) / 256;
    unfold9_lin<<<blocks, 256, 0, stream>>>(left, right, out);
    onehot_kernel<<<1, 128, 0, stream>>>(out + (size_t)2 * N_FEAT);
}

// Round 4
// 447.837 us; speedup vs baseline: 1.0063x; 1.0063x over previous
//
#include <hip/hip_runtime.h>

// Problem constants (reference: B=4, C=3, H=384, W=1248, FILTER_SIZE=3)
#define B_ 4
#define C_ 3
#define H_ 384
#define W_ 1248
#define KK_ 9               // F*F
#define W4_ (W_ / 4)        // 312

constexpr int N_FEAT  = B_ * KK_ * C_ * H_ * W_;  // 51,757,056 per tensor
constexpr int PLANE4  = H_ * W4_;                 // 119,808 float4s per (s,b,k,c) plane
constexpr int BLOCKS_X = PLANE4 / 256;            // 468 (exact, no tail)
constexpr int PLANES   = 2 * B_ * KK_ * C_;       // 216

typedef float vf4 __attribute__((ext_vector_type(4)));

// v5: 2-D grid. blockIdx.y = plane index ((s*B+b)*KK+k)*C+c — decoded entirely
// in uniform/scalar registers (zero per-lane VALU). Per-lane work: one magic
// div by 312 (y,x4), one dwordx4 load (L3-resident input), one nt dwordx4
// store into a perfectly linear device-wide stream. This is within ~2 VALU of
// the harness fill kernel's instruction mix, which sustains 6.3 TB/s on this
// same buffer. Branches on dx are wave-uniform; only the x-edge lanes
// (x4==0 or x4==311) take the shift-patch path.
__global__ __launch_bounds__(256) void unfold9_v5(
    const float* __restrict__ left,
    const float* __restrict__ right,
    float* __restrict__ out)
{
    // Uniform plane decode (SALU only)
    const int pb = blockIdx.y;              // ((s*B+b)*KK+k)*C + c
    const int c  = pb % C_;
    const int k  = (pb / C_) % KK_;
    const int b  = (pb / (C_ * KK_)) % B_;
    const int s  = pb / (C_ * KK_ * B_);
    const int dy = k / 3;
    const int dx = k % 3;

    // Per-lane decode: one div by 312
    const int rem = blockIdx.x * 256 + threadIdx.x;   // 0..119807
    const int y   = rem / W4_;
    const int x4  = rem - y * W4_;
    const int x0  = x4 * 4;
    const int yin = y + dy - 1;

    vf4 v = (vf4){0.f, 0.f, 0.f, 0.f};
    if (yin >= 0 && yin < H_) {
        const float* rp = (s ? right : left)
                        + (size_t)((b * C_ + c) * H_ + yin) * W_;
        if (dx == 1) {                        // aligned
            v = *reinterpret_cast<const vf4*>(rp + x0);
        } else if (dx == 0) {                 // src x = [x0-1 .. x0+2]
            if (x4 > 0) {
                v = *reinterpret_cast<const vf4*>(rp + x0 - 1);
            } else {
                vf4 a = *reinterpret_cast<const vf4*>(rp);
                v = (vf4){0.f, a.x, a.y, a.z};
            }
        } else {                              // dx==2: src x = [x0+1 .. x0+4]
            if (x4 < W4_ - 1) {
                v = *reinterpret_cast<const vf4*>(rp + x0 + 1);
            } else {
                vf4 a = *reinterpret_cast<const vf4*>(rp + x0);
                v = (vf4){a.y, a.z, a.w, 0.f};
            }
        }
    }

    // out flat float4 index = pb*PLANE4 + rem  (layout [s][b][k][c][y][x])
    float* op = out + (size_t)pb * ((size_t)H_ * W_) + (size_t)rem * 4;
    __builtin_nontemporal_store(v, reinterpret_cast<vf4*>(op));
}

// one_hot_filter = eye(9).reshape(9,1,1,3,3): flat[i] = (i % 10 == 0)
__global__ void onehot_kernel(float* __restrict__ out)
{
    int i = threadIdx.x;
    if (i < KK_ * KK_) out[i] = (i % 10 == 0) ? 1.0f : 0.0f;
}

extern "C" void kernel_launch(void* const* d_in, const int* in_sizes, int n_in,
                              void* d_out, int out_size, void* d_ws, size_t ws_size,
                              hipStream_t stream)
{
    const float* left  = (const float*)d_in[0];
    const float* right = (const float*)d_in[1];
    float* out = (float*)d_out;

    dim3 grid(BLOCKS_X, PLANES);
    unfold9_v5<<<grid, 256, 0, stream>>>(left, right, out);
    onehot_kernel<<<1, 128, 0, stream>>>(out + (size_t)2 * N_FEAT);
}